// Round 2
// baseline (441.226 us; speedup 1.0000x reference)
//
#include <hip/hip_runtime.h>

// Classifier: out[40000][10] = (mean_J relu(x @ Wloc^T)) @ W^T
// x: [1200000][64] f32, Wloc: [128][64] f32, W: [10][128] f32.
// Strategy: bf16 MFMA (16x16x32); ONE wave per block owning 16 segments
// (2500 blocks -> 9.77 waves/CU, ~2% imbalance vs 23% with 625x4-wave blocks).
// M-tile = one row per segment at offset r, r=0..29; relu+pool in registers.
// Memory floor: 307 MB x read-once / 6.3 TB/s ~= 49 us.

typedef __bf16 bf16x8 __attribute__((ext_vector_type(8)));
typedef float f32x4 __attribute__((ext_vector_type(4)));

#define JJ 30
#define DIN 64
#define DENC 128
#define NCLS 10
#define SEG_PER_BLOCK 16
#define FEATP 132          // padded stride (floats): keeps float4 alignment,
                           // 528 B % 128 = 16 -> bank rotation, no hot bank

union FragU { unsigned u[4]; bf16x8 v; };

// pack two f32 -> one dword of two bf16 (round-to-nearest-ish via +0x8000,
// v_perm_b32 grabs high halves). hi -> bits 31:16, lo -> 15:0.
__device__ __forceinline__ unsigned pk_rn(float hi, float lo) {
  unsigned uh = __builtin_bit_cast(unsigned, hi) + 0x8000u;
  unsigned ul = __builtin_bit_cast(unsigned, lo) + 0x8000u;
  return __builtin_amdgcn_perm(uh, ul, 0x07060302u);
}

__global__ __launch_bounds__(64)
void classifier_kernel(const float* __restrict__ x,
                       const float* __restrict__ wloc,
                       const float* __restrict__ w,
                       float* __restrict__ out) {
  __shared__ float s_feats[SEG_PER_BLOCK * FEATP]; // 8448 B
  __shared__ float s_w[NCLS * FEATP];              // 5280 B (padded stride)

  const int lane = threadIdx.x & 63;
  const int quad = lane >> 4;
  const int lrow = lane & 15;

  // stage W into LDS (float4, padded stride 132 floats = 33 float4)
  {
    const float4* wg = (const float4*)w;          // 320 float4s
    for (int g = lane; g < NCLS * (DENC / 4); g += 64) {
      int c = g >> 5, e4 = g & 31;                // 32 float4 per class row
      ((float4*)s_w)[c * (FEATP / 4) + e4] = wg[g];
    }
  }

  // B fragments: whole Wloc in registers. B-operand lane -> (n=lrow, k=quad*8+j)
  // element = Wloc[e = nt*16 + lrow][d = ks*32 + quad*8 + j]
  FragU wb[8][2];
#pragma unroll
  for (int nt = 0; nt < 8; ++nt) {
#pragma unroll
    for (int ks = 0; ks < 2; ++ks) {
      const float* p = wloc + (nt * 16 + lrow) * DIN + ks * 32 + quad * 8;
      float4 f0 = *(const float4*)p;
      float4 f1 = *(const float4*)(p + 4);
      wb[nt][ks].u[0] = pk_rn(f0.y, f0.x);
      wb[nt][ks].u[1] = pk_rn(f0.w, f0.z);
      wb[nt][ks].u[2] = pk_rn(f1.y, f1.x);
      wb[nt][ks].u[3] = pk_rn(f1.w, f1.z);
    }
  }

  const int seg0 = blockIdx.x * SEG_PER_BLOCK;
  // A-frag rows: m = lrow -> segment seg0+lrow, row offset r, k = quad*8+j
  const float* xbase = x + (size_t)(seg0 + lrow) * (JJ * DIN) + quad * 8;

  float segsum[8][4];
#pragma unroll
  for (int nt = 0; nt < 8; ++nt)
#pragma unroll
    for (int rg = 0; rg < 4; ++rg) segsum[nt][rg] = 0.f;

#pragma unroll 2
  for (int r = 0; r < JJ; ++r) {
    const float* p = xbase + (size_t)r * DIN;
    float4 v0 = *(const float4*)p;
    float4 v1 = *(const float4*)(p + 4);
    float4 v2 = *(const float4*)(p + 32);
    float4 v3 = *(const float4*)(p + 36);
    FragU a0, a1;
    a0.u[0] = pk_rn(v0.y, v0.x); a0.u[1] = pk_rn(v0.w, v0.z);
    a0.u[2] = pk_rn(v1.y, v1.x); a0.u[3] = pk_rn(v1.w, v1.z);
    a1.u[0] = pk_rn(v2.y, v2.x); a1.u[1] = pk_rn(v2.w, v2.z);
    a1.u[2] = pk_rn(v3.y, v3.x); a1.u[3] = pk_rn(v3.w, v3.z);
#pragma unroll
    for (int nt = 0; nt < 8; ++nt) {
      f32x4 z = {0.f, 0.f, 0.f, 0.f};
      f32x4 acc = __builtin_amdgcn_mfma_f32_16x16x32_bf16(a0.v, wb[nt][0].v, z, 0, 0, 0);
      acc = __builtin_amdgcn_mfma_f32_16x16x32_bf16(a1.v, wb[nt][1].v, acc, 0, 0, 0);
      // C/D layout: row (=segment within wave) = quad*4+rg, col = nt*16+lrow
#pragma unroll
      for (int rg = 0; rg < 4; ++rg)
        segsum[nt][rg] += fmaxf(acc[rg], 0.f);
    }
  }

  // feats (mean) -> LDS. Bank check: addr%32 = (quad*16 + lrow + c)%32 -> 2-way, free.
  const float inv = 1.0f / 30.0f;
#pragma unroll
  for (int nt = 0; nt < 8; ++nt) {
#pragma unroll
    for (int rg = 0; rg < 4; ++rg) {
      int segl = quad * 4 + rg;
      s_feats[segl * FEATP + nt * 16 + lrow] = segsum[nt][rg] * inv;
    }
  }
  __syncthreads();

  // final tiny matmul: 160 outputs, float4 dots from LDS.
  for (int i = lane; i < SEG_PER_BLOCK * NCLS; i += 64) {
    int sg = i / NCLS;
    int c  = i - sg * NCLS;
    const float4* fr = (const float4*)(s_feats + sg * FEATP);
    const float4* wr = (const float4*)(s_w + c * FEATP);
    float4 a = {0.f, 0.f, 0.f, 0.f};
#pragma unroll
    for (int e = 0; e < DENC / 4; ++e) {
      float4 f = fr[e], g = wr[e];
      a.x += f.x * g.x; a.y += f.y * g.y;
      a.z += f.z * g.z; a.w += f.w * g.w;
    }
    out[(size_t)(seg0 + sg) * NCLS + c] = (a.x + a.y) + (a.z + a.w);
  }
}

extern "C" void kernel_launch(void* const* d_in, const int* in_sizes, int n_in,
                              void* d_out, int out_size, void* d_ws, size_t ws_size,
                              hipStream_t stream) {
  const float* x    = (const float*)d_in[0];
  const float* wloc = (const float*)d_in[1];
  const float* w    = (const float*)d_in[2];
  float* out = (float*)d_out;
  // 40000 segments / 16 per block = 2500 blocks exactly
  classifier_kernel<<<dim3(2500), dim3(64), 0, stream>>>(x, wloc, w, out);
}